// Round 13
// baseline (696.214 us; speedup 1.0000x reference)
//
#include <hip/hip_runtime.h>
#include <hip/hip_bf16.h>

#define D 128
#define BN_EPS 1e-5f
#define NBG 2048                   // gather grid blocks (256 per panel)
#define CHUNK 4096                 // edges per block in h1/scatter
#define CAP 6144                   // max edges per coarse bin

typedef unsigned short u16;
typedef unsigned int u32;
typedef unsigned long long u64;
typedef __attribute__((ext_vector_type(8))) short bf16x8;
typedef __attribute__((ext_vector_type(4))) float f32x4;

__device__ __forceinline__ float bf2f(u16 u) {
    unsigned v = (unsigned)u << 16; float f; __builtin_memcpy(&f, &v, 4); return f;
}
__device__ __forceinline__ u16 f2bf(float f) {
    __hip_bfloat16 h = __float2bfloat16(f);
    u16 r; __builtin_memcpy(&r, &h, 2); return r;
}

__device__ __forceinline__ int wscan_incl(int v, int lane) {
    int inc = v;
#pragma unroll
    for (int off = 1; off < 64; off <<= 1) {
        int t = __shfl_up(inc, (unsigned)off, 64);
        if (lane >= off) inc += t;
    }
    return inc;
}

// ---------------- fused: W^T->bf16 (x3) + zero gcount + rowptr[N]=E ----------------
__global__ __launch_bounds__(256) void k_wtz(const float* __restrict__ W1, const float* __restrict__ W2,
                                             const float* __restrict__ W3, u16* __restrict__ Wt1,
                                             u16* __restrict__ Wt2, u16* __restrict__ Wt3,
                                             int* __restrict__ zp, int nz, int* __restrict__ rowptrN, int E)
{
    int bid = blockIdx.x;
    if (bid < 192) {
        int w = bid >> 6;
        int i = (bid & 63) * 256 + threadIdx.x;     // i = k*128 + c
        int k = i >> 7, c = i & 127;
        const float* W = w == 0 ? W1 : (w == 1 ? W2 : W3);
        u16* Wt = w == 0 ? Wt1 : (w == 1 ? Wt2 : Wt3);
        Wt[c * D + k] = f2bf(W[i]);
    } else {
        if (bid == 192 && threadIdx.x == 0) *rowptrN = E;
        int i = (bid - 192) * 256 + threadIdx.x;
        if (i < nz) zp[i] = 0;
    }
}

// ---------------- counting sort level 1: coarse histogram (LDS) ----------------
__global__ __launch_bounds__(256) void k_h1(const int* __restrict__ ei, int* __restrict__ gcount,
                                            int* __restrict__ gbase, int E, int ncb)
{
    __shared__ int cnt[512];
    for (int i = threadIdx.x; i < ncb; i += 256) cnt[i] = 0;
    __syncthreads();
    int base = blockIdx.x * CHUNK;
    int lim = base + CHUNK < E ? base + CHUNK : E;
    for (int e = base + threadIdx.x; e < lim; e += 256) {
        int d = ei[(size_t)E + e];
        atomicAdd(&cnt[d >> 8], 1);
    }
    __syncthreads();
    for (int b = threadIdx.x; b < ncb; b += 256) {
        int c = cnt[b];
        if (c) gbase[(size_t)blockIdx.x * ncb + b] = atomicAdd(&gcount[b], c);
    }
}

// ---------------- scatter edges into coarse-bin order (in-LDS goff scan) ----------------
__global__ __launch_bounds__(256) void k_scatter(const int* __restrict__ ei, const float* __restrict__ ew,
                                                 const int* __restrict__ gcount, const int* __restrict__ gbase,
                                                 u64* __restrict__ bkv, int E, int ncb)
{
    __shared__ int goffL[512];
    __shared__ int cnt[512];
    int t = threadIdx.x, lane = t & 63;
    if (t < 64) {
        int carry = 0;
        for (int base = 0; base < ncb; base += 64) {
            int i = base + lane;
            int v = (i < ncb) ? gcount[i] : 0;
            int inc = wscan_incl(v, lane);
            if (i < ncb) goffL[i] = carry + inc - v;
            carry += __shfl(inc, 63, 64);
        }
    }
    for (int i = t; i < ncb; i += 256) cnt[i] = 0;
    __syncthreads();
    int base = blockIdx.x * CHUNK;
    int lim = base + CHUNK < E ? base + CHUNK : E;
    for (int e = base + t; e < lim; e += 256) {
        int s = ei[e];
        int d = ei[(size_t)E + e];
        int b = d >> 8;
        int r = atomicAdd(&cnt[b], 1);
        int pos = goffL[b] + gbase[(size_t)blockIdx.x * ncb + b] + r;
        u32 key = ((u32)s << 8) | (u32)(d & 255);
        u32 wb; __builtin_memcpy(&wb, &ew[e], 4);
        bkv[pos] = ((u64)key << 32) | (u64)wb;
    }
}

// ---------------- fine pass: per coarse bin -> rowptr, dinv, cv (raw weights) ----------------
__global__ __launch_bounds__(256) void k_fine(const u64* __restrict__ bkv, const int* __restrict__ gcount,
                                              int* __restrict__ rowptr, float* __restrict__ dinv,
                                              int2* __restrict__ cv, int N, int ncb)
{
    __shared__ int goffL[513];
    __shared__ int cnt[256];
    __shared__ float wsum[256];
    __shared__ u16 lrank[CAP];
    __shared__ int lrp[256];
    __shared__ int wtot[4];
    int b = blockIdx.x, t = threadIdx.x;
    int lane = t & 63, wv = t >> 6;
    if (t < 64) {
        int carry = 0;
        for (int base = 0; base < ncb; base += 64) {
            int i = base + lane;
            int v = (i < ncb) ? gcount[i] : 0;
            int inc = wscan_incl(v, lane);
            if (i < ncb) goffL[i] = carry + inc - v;
            carry += __shfl(inc, 63, 64);
        }
        if (lane == 0) goffL[ncb] = carry;
    }
    cnt[t] = 0; wsum[t] = 0.f;
    __syncthreads();
    int s0 = goffL[b], s1 = goffL[b + 1];
    int n = s1 - s0;
    for (int i = t; i < n; i += 256) {
        u64 kv = bkv[s0 + i];
        int bin = (int)((kv >> 32) & 255);
        u32 wb = (u32)kv; float w; __builtin_memcpy(&w, &wb, 4);
        int r = atomicAdd(&cnt[bin], 1);
        if (i < CAP) lrank[i] = (u16)r;
        atomicAdd(&wsum[bin], w);
    }
    __syncthreads();
    int v = cnt[t];
    int inc = wscan_incl(v, lane);
    if (lane == 63) wtot[wv] = inc;
    __syncthreads();
    int woff = 0;
#pragma unroll
    for (int w = 0; w < 4; ++w) woff += (w < wv) ? wtot[w] : 0;
    int excl = woff + inc - v;
    lrp[t] = excl;
    int d = b * 256 + t;
    if (d < N) {
        rowptr[d] = s0 + excl;
        dinv[d] = rsqrtf(wsum[t] + 1.0f);     // +1 = self-loop weight
    }
    __syncthreads();
    for (int i = t; i < n; i += 256) {
        if (i >= CAP) break;
        u64 kv = bkv[s0 + i];
        int key = (int)(kv >> 32);
        int bin = key & 255;
        int src = key >> 8;
        int pos = s0 + lrp[bin] + (int)lrank[i];
        cv[pos] = make_int2(src, (int)(u32)kv);   // raw ew; norm applied in gather
    }
}

// ---------------- GEMM body: Hp (8 column panels of 16, bf16) = f(X) @ W ----------------
template <int FUSE_BN, int INB>
__device__ __forceinline__ void gemm_body(const void* __restrict__ Xv, const u16* __restrict__ Wt,
                                          u16* __restrict__ H, int N, const float* __restrict__ ss, int bid)
{
    int tid = threadIdx.x;
    int wv = tid >> 6, lane = tid & 63;
    int colA = lane & 15, oct = lane >> 4;
    int r0 = bid * 64;
    int c0 = wv * 32;

    bf16x8 bfr[2][4];
#pragma unroll
    for (int t = 0; t < 2; ++t)
#pragma unroll
        for (int kk = 0; kk < 4; ++kk)
            bfr[t][kk] = *(const bf16x8*)(Wt + (size_t)(c0 + t * 16 + colA) * D + kk * 32 + oct * 8);

    float4 sc[8], sh[8];
    if (FUSE_BN) {
#pragma unroll
        for (int kk = 0; kk < 4; ++kk) {
            sc[kk * 2 + 0] = *(const float4*)(ss + kk * 32 + oct * 8);
            sc[kk * 2 + 1] = *(const float4*)(ss + kk * 32 + oct * 8 + 4);
            sh[kk * 2 + 0] = *(const float4*)(ss + D + kk * 32 + oct * 8);
            sh[kk * 2 + 1] = *(const float4*)(ss + D + kk * 32 + oct * 8 + 4);
        }
    }

    for (int rs = 0; rs < 4; ++rs) {
        int r = r0 + rs * 16;
        int rr = r + colA; rr = rr < N ? rr : N - 1;          // clamp loads; stores guarded
        f32x4 acc0 = {0.f, 0.f, 0.f, 0.f}, acc1 = {0.f, 0.f, 0.f, 0.f};
#pragma unroll
        for (int kk = 0; kk < 4; ++kk) {
            bf16x8 a;
            if (!INB) {
                const float* xrow = (const float*)Xv + (size_t)rr * D + oct * 8;
                float4 xa = *(const float4*)(xrow + kk * 32);
                float4 xb = *(const float4*)(xrow + kk * 32 + 4);
                a[0] = (short)f2bf(xa.x); a[1] = (short)f2bf(xa.y);
                a[2] = (short)f2bf(xa.z); a[3] = (short)f2bf(xa.w);
                a[4] = (short)f2bf(xb.x); a[5] = (short)f2bf(xb.y);
                a[6] = (short)f2bf(xb.z); a[7] = (short)f2bf(xb.w);
            } else {
                const u16* brow = (const u16*)Xv + (size_t)rr * D + oct * 8;
                bf16x8 v = *(const bf16x8*)(brow + kk * 32);
                if (FUSE_BN) {
                    float4 s0 = sc[kk * 2], s1 = sc[kk * 2 + 1];
                    float4 h0 = sh[kk * 2], h1 = sh[kk * 2 + 1];
                    a[0] = (short)f2bf(fmaxf(fmaf(bf2f((u16)v[0]), s0.x, h0.x), 0.f));
                    a[1] = (short)f2bf(fmaxf(fmaf(bf2f((u16)v[1]), s0.y, h0.y), 0.f));
                    a[2] = (short)f2bf(fmaxf(fmaf(bf2f((u16)v[2]), s0.z, h0.z), 0.f));
                    a[3] = (short)f2bf(fmaxf(fmaf(bf2f((u16)v[3]), s0.w, h0.w), 0.f));
                    a[4] = (short)f2bf(fmaxf(fmaf(bf2f((u16)v[4]), s1.x, h1.x), 0.f));
                    a[5] = (short)f2bf(fmaxf(fmaf(bf2f((u16)v[5]), s1.y, h1.y), 0.f));
                    a[6] = (short)f2bf(fmaxf(fmaf(bf2f((u16)v[6]), s1.z, h1.z), 0.f));
                    a[7] = (short)f2bf(fmaxf(fmaf(bf2f((u16)v[7]), s1.w, h1.w), 0.f));
                } else {
                    a = v;
                }
            }
            acc0 = __builtin_amdgcn_mfma_f32_16x16x32_bf16(a, bfr[0][kk], acc0, 0, 0, 0);
            acc1 = __builtin_amdgcn_mfma_f32_16x16x32_bf16(a, bfr[1][kk], acc1, 0, 0, 0);
        }
        int orow = r + oct * 4;
        int p1 = wv * 2, p2 = wv * 2 + 1;        // panel ids for cols c0+colA, c0+colA+16
#pragma unroll
        for (int j = 0; j < 4; ++j) {
            if (orow + j < N) {
                H[((size_t)p1 * N + orow + j) * 16 + colA] = f2bf(acc0[j]);
                H[((size_t)p2 * N + orow + j) * 16 + colA] = f2bf(acc1[j]);
            }
        }
    }
}

template <int FUSE_BN, int INB>
__global__ __launch_bounds__(256) void k_gemm(const void* __restrict__ Xv, const u16* __restrict__ Wt,
                                              u16* __restrict__ H, int N, const float* __restrict__ ss)
{
    gemm_body<FUSE_BN, INB>(Xv, Wt, H, N, ss, blockIdx.x);
}

// ---------------- panel gather: block handles panel p=bid&7 (XCD-pinned working set) ----------
// wave = 8 row-groups x 8 lanes; lane covers 2 cols of its panel. Norm folded in (raw ew in cv).
template <int OUTB>
__global__ __launch_bounds__(256) void k_gather(const u16* __restrict__ hp, const int* __restrict__ rowptr,
                                                const int2* __restrict__ cv, const float* __restrict__ dinv,
                                                const float* __restrict__ bias, u16* __restrict__ outb,
                                                float* __restrict__ outf, float* __restrict__ partial,
                                                int N, int nbg)
{
    int t = threadIdx.x;
    int lane = t & 63, wv = t >> 6;
    int cl = lane & 7, g = lane >> 3;
    int p = blockIdx.x & 7;
    int q = blockIdx.x >> 3;
    const u16* hpan = hp + (size_t)p * N * 16;
    int slots = (nbg >> 3) * 32;              // row slots per panel set
    int slot0 = q * 32 + wv * 8 + g;
    float2 bv = ((const float2*)(bias + p * 16))[cl];
    float4 st = {0.f, 0.f, 0.f, 0.f};
    for (int row = slot0; row < N; row += slots) {
        float dd = dinv[row];
        float sw = dd * dd;
        ushort2 hv = ((const ushort2*)(hpan + (size_t)row * 16))[cl];
        float ax = bf2f(hv.x) * sw, ay = bf2f(hv.y) * sw;
        int j = rowptr[row], end = rowptr[row + 1];
        for (; j + 4 <= end; j += 4) {
            int2 e0 = cv[j], e1 = cv[j + 1], e2 = cv[j + 2], e3 = cv[j + 3];
            float w0 = __int_as_float(e0.y) * dinv[e0.x] * dd;
            float w1 = __int_as_float(e1.y) * dinv[e1.x] * dd;
            float w2 = __int_as_float(e2.y) * dinv[e2.x] * dd;
            float w3 = __int_as_float(e3.y) * dinv[e3.x] * dd;
            ushort2 v0 = ((const ushort2*)(hpan + (size_t)e0.x * 16))[cl];
            ushort2 v1 = ((const ushort2*)(hpan + (size_t)e1.x * 16))[cl];
            ushort2 v2 = ((const ushort2*)(hpan + (size_t)e2.x * 16))[cl];
            ushort2 v3 = ((const ushort2*)(hpan + (size_t)e3.x * 16))[cl];
            ax = fmaf(w0, bf2f(v0.x), ax); ay = fmaf(w0, bf2f(v0.y), ay);
            ax = fmaf(w1, bf2f(v1.x), ax); ay = fmaf(w1, bf2f(v1.y), ay);
            ax = fmaf(w2, bf2f(v2.x), ax); ay = fmaf(w2, bf2f(v2.y), ay);
            ax = fmaf(w3, bf2f(v3.x), ax); ay = fmaf(w3, bf2f(v3.y), ay);
        }
        for (; j < end; ++j) {
            int2 e0 = cv[j];
            float w0 = __int_as_float(e0.y) * dinv[e0.x] * dd;
            ushort2 v0 = ((const ushort2*)(hpan + (size_t)e0.x * 16))[cl];
            ax = fmaf(w0, bf2f(v0.x), ax); ay = fmaf(w0, bf2f(v0.y), ay);
        }
        float ox = ax + bv.x, oy = ay + bv.y;
        if (OUTB) {
            ushort2 ob; ob.x = f2bf(ox); ob.y = f2bf(oy);
            ((ushort2*)(outb + (size_t)row * D + p * 16))[cl] = ob;
        } else {
            float2 o; o.x = ox; o.y = oy;
            ((float2*)(outf + (size_t)row * D + p * 16))[cl] = o;
        }
        st.x += ox; st.y = fmaf(ox, ox, st.y);
        st.z += oy; st.w = fmaf(oy, oy, st.w);
    }
    // reduce across the 8 groups (lanes with same cl)
#pragma unroll
    for (int m = 8; m < 64; m <<= 1) {
        st.x += __shfl_xor(st.x, m, 64);
        st.y += __shfl_xor(st.y, m, 64);
        st.z += __shfl_xor(st.z, m, 64);
        st.w += __shfl_xor(st.w, m, 64);
    }
    __shared__ float4 red[4][8];
    if (lane < 8) red[wv][lane] = st;
    __syncthreads();
    if (t < 8) {
        float4 a0 = red[0][t], a1 = red[1][t], a2 = red[2][t], a3 = red[3][t];
        float4 o;
        o.x = a0.x + a1.x + a2.x + a3.x;
        o.y = a0.y + a1.y + a2.y + a3.y;
        o.z = a0.z + a1.z + a2.z + a3.z;
        o.w = a0.w + a1.w + a2.w + a3.w;
        ((float4*)partial)[(size_t)blockIdx.x * 8 + t] = o;   // [sum,sq] x 2 cols per colpair
    }
}

// ---------------- reduce partials -> BN scale/shift ----------------
// col c: panel p=c>>4, colpair cp=(c>>1)&7, part=c&1; blocks with bid&7==p.
__global__ __launch_bounds__(256) void k_bnred(const float* __restrict__ partial, int nbg,
                                               const float* __restrict__ g, const float* __restrict__ be,
                                               float* __restrict__ ss, float invN)
{
    int c = blockIdx.x;
    int p = c >> 4, cp = (c >> 1) & 7, part = c & 1;
    int nb8 = nbg >> 3;
    int t = threadIdx.x;
    float s = 0.f, s2 = 0.f;
    for (int bb = t; bb < nb8; bb += 256) {
        const float* row = partial + ((size_t)(bb * 8 + p) * 8 + cp) * 4 + part * 2;
        s += row[0]; s2 += row[1];
    }
#pragma unroll
    for (int off = 32; off; off >>= 1) {
        s  += __shfl_down(s,  (unsigned)off, 64);
        s2 += __shfl_down(s2, (unsigned)off, 64);
    }
    __shared__ float rs_[4], rq_[4];
    int wv = t >> 6, lane = t & 63;
    if (lane == 0) { rs_[wv] = s; rq_[wv] = s2; }
    __syncthreads();
    if (t == 0) {
        float S = rs_[0] + rs_[1] + rs_[2] + rs_[3];
        float Q = rq_[0] + rq_[1] + rq_[2] + rq_[3];
        float mu = S * invN;
        float var = fmaxf(Q * invN - mu * mu, 0.f);
        float r = rsqrtf(var + BN_EPS);
        float sc = r * g[c];
        ss[c] = sc;
        ss[D + c] = be[c] - mu * sc;
    }
}

// final BN apply: y = x*sc + sh
__global__ __launch_bounds__(256) void k_bnapply(const float* __restrict__ in, const float* __restrict__ ss,
                                                 float* __restrict__ out, int N)
{
    int idx = blockIdx.x * 256 + threadIdx.x;
    if (idx >= N * 32) return;
    int cc = idx & 31;
    float4 xv = ((const float4*)in)[idx];
    float4 sc = ((const float4*)ss)[cc];
    float4 sh = ((const float4*)(ss + D))[cc];
    float4 o;
    o.x = fmaf(xv.x, sc.x, sh.x);
    o.y = fmaf(xv.y, sc.y, sh.y);
    o.z = fmaf(xv.z, sc.z, sh.z);
    o.w = fmaf(xv.w, sc.w, sh.w);
    ((float4*)out)[idx] = o;
}

// ---------------- launch ----------------
extern "C" void kernel_launch(void* const* d_in, const int* in_sizes, int n_in,
                              void* d_out, int out_size, void* d_ws, size_t ws_size,
                              hipStream_t stream)
{
    const float* x  = (const float*)d_in[0];
    const int*   ei = (const int*)d_in[1];      // int32 on device
    const float* ew = (const float*)d_in[2];
    const float* W1 = (const float*)d_in[4];
    const float* b1 = (const float*)d_in[5];
    const float* W2 = (const float*)d_in[6];
    const float* b2 = (const float*)d_in[7];
    const float* W3 = (const float*)d_in[8];
    const float* b3 = (const float*)d_in[9];
    const float* g1 = (const float*)d_in[10];
    const float* be1 = (const float*)d_in[11];
    const float* g2 = (const float*)d_in[12];
    const float* be2 = (const float*)d_in[13];
    const float* g3 = (const float*)d_in[14];
    const float* be3 = (const float*)d_in[15];

    int N = in_sizes[0] / D;
    int E = in_sizes[1] / 2;
    float* P  = (float*)d_out;                       // final f32 activations / output
    u16*   Pb = (u16*)d_out;                         // bf16 inter-layer activations
    u64*   bkv = (u64*)((char*)d_out + ((size_t)32 << 20));  // binned edges; dead before gathers

    char* ws = (char*)d_ws;
    size_t off = 0;
    auto alloc = [&](size_t bytes) -> void* {
        void* p = ws + off;
        off = (off + bytes + 255) & ~(size_t)255;
        return p;
    };
    int ncb = (N + 255) >> 8;                        // coarse bins (256 dsts each)
    int hb  = (E + CHUNK - 1) / CHUNK;               // h1/scatter blocks
    u16*   Hb    = (u16*)alloc((size_t)N * D * 2);   // bf16 GEMM output, 8 column panels
    float* dinv  = (float*)alloc((size_t)N * 4);
    int*   rowptr= (int*)alloc((size_t)(N + 1) * 4);
    int2*  cv    = (int2*)alloc((size_t)E * 8);      // (src, raw ew)
    float* partial = (float*)alloc((size_t)NBG * 32 * 4);
    int*   gcount= (int*)alloc((size_t)(ncb + 1) * 4);
    int*   gbase = (int*)alloc((size_t)hb * ncb * 4);
    float* ss1   = (float*)alloc(1024);
    float* ss2   = (float*)alloc(1024);
    float* ss3   = (float*)alloc(1024);
    u16*   Wt1   = (u16*)alloc((size_t)D * D * 2);
    u16*   Wt2   = (u16*)alloc((size_t)D * D * 2);
    u16*   Wt3   = (u16*)alloc((size_t)D * D * 2);

    float invN = 1.0f / (float)N;
    int ggrid = (N + 63) / 64;
    int pgrid = (N * 32 + 255) / 256;
    int nbg   = NBG;
    int zgrid = (ncb + 256) / 256;

    // ---- prep: weights + zero gcount (+rowptr[N]=E), gemm0, counting-sort CSR build ----
    k_wtz<<<192 + zgrid, 256, 0, stream>>>(W1, W2, W3, Wt1, Wt2, Wt3, gcount, ncb, rowptr + N, E);
    k_gemm<0, 0><<<ggrid, 256, 0, stream>>>(x, Wt1, Hb, N, nullptr);
    k_h1<<<hb, 256, 0, stream>>>(ei, gcount, gbase, E, ncb);
    k_scatter<<<hb, 256, 0, stream>>>(ei, ew, gcount, gbase, bkv, E, ncb);
    k_fine<<<ncb, 256, 0, stream>>>(bkv, gcount, rowptr, dinv, cv, N, ncb);

    // ---- layer 1 ----
    k_gather<1><<<nbg, 256, 0, stream>>>(Hb, rowptr, cv, dinv, b1, Pb, nullptr, partial, N, nbg);
    k_bnred<<<D, 256, 0, stream>>>(partial, nbg, g1, be1, ss1, invN);

    // ---- layer 2 (BN1+ReLU fused into gemm, bf16 in) ----
    k_gemm<1, 1><<<ggrid, 256, 0, stream>>>(Pb, Wt2, Hb, N, ss1);
    k_gather<1><<<nbg, 256, 0, stream>>>(Hb, rowptr, cv, dinv, b2, Pb, nullptr, partial, N, nbg);
    k_bnred<<<D, 256, 0, stream>>>(partial, nbg, g2, be2, ss2, invN);

    // ---- layer 3 (BN2+ReLU fused into gemm; final BN explicit) ----
    k_gemm<1, 1><<<ggrid, 256, 0, stream>>>(Pb, Wt3, Hb, N, ss2);
    k_gather<0><<<nbg, 256, 0, stream>>>(Hb, rowptr, cv, dinv, b3, nullptr, P, partial, N, nbg);
    k_bnred<<<D, 256, 0, stream>>>(partial, nbg, g3, be3, ss3, invN);
    k_bnapply<<<pgrid, 256, 0, stream>>>(P, ss3, P, N);
}

// Round 16
// 412.439 us; speedup vs baseline: 1.6880x; 1.6880x over previous
//
#include <hip/hip_runtime.h>
#include <hip/hip_bf16.h>

#define D 128
#define BN_EPS 1e-5f
#define NBG 2048                   // gather grid blocks
#define CHUNK 4096                 // edges per block in h1/scatter
#define CAP 6144                   // max edges per coarse bin

typedef unsigned short u16;
typedef unsigned int u32;
typedef unsigned long long u64;
typedef __attribute__((ext_vector_type(8))) short bf16x8;
typedef __attribute__((ext_vector_type(4))) float f32x4;

__device__ __forceinline__ float bf2f(u16 u) {
    unsigned v = (unsigned)u << 16; float f; __builtin_memcpy(&f, &v, 4); return f;
}
__device__ __forceinline__ u16 f2bf(float f) {
    __hip_bfloat16 h = __float2bfloat16(f);
    u16 r; __builtin_memcpy(&r, &h, 2); return r;
}

__device__ __forceinline__ int wscan_incl(int v, int lane) {
    int inc = v;
#pragma unroll
    for (int off = 1; off < 64; off <<= 1) {
        int t = __shfl_up(inc, (unsigned)off, 64);
        if (lane >= off) inc += t;
    }
    return inc;
}

// ---------------- fused: W^T->bf16 (x3) + zero gcount + rowptr[N]=E ----------------
__global__ __launch_bounds__(256) void k_wtz(const float* __restrict__ W1, const float* __restrict__ W2,
                                             const float* __restrict__ W3, u16* __restrict__ Wt1,
                                             u16* __restrict__ Wt2, u16* __restrict__ Wt3,
                                             int* __restrict__ zp, int nz, int* __restrict__ rowptrN, int E)
{
    int bid = blockIdx.x;
    if (bid < 192) {
        int w = bid >> 6;
        int i = (bid & 63) * 256 + threadIdx.x;     // i = k*128 + c
        int k = i >> 7, c = i & 127;
        const float* W = w == 0 ? W1 : (w == 1 ? W2 : W3);
        u16* Wt = w == 0 ? Wt1 : (w == 1 ? Wt2 : Wt3);
        Wt[c * D + k] = f2bf(W[i]);
    } else {
        if (bid == 192 && threadIdx.x == 0) *rowptrN = E;
        int i = (bid - 192) * 256 + threadIdx.x;
        if (i < nz) zp[i] = 0;
    }
}

// ---------------- counting sort level 1: coarse histogram (LDS) ----------------
__global__ __launch_bounds__(256) void k_h1(const int* __restrict__ ei, int* __restrict__ gcount,
                                            int* __restrict__ gbase, int E, int ncb)
{
    __shared__ int cnt[512];
    for (int i = threadIdx.x; i < ncb; i += 256) cnt[i] = 0;
    __syncthreads();
    int base = blockIdx.x * CHUNK;
    int lim = base + CHUNK < E ? base + CHUNK : E;
    for (int e = base + threadIdx.x; e < lim; e += 256) {
        int d = ei[(size_t)E + e];
        atomicAdd(&cnt[d >> 8], 1);
    }
    __syncthreads();
    for (int b = threadIdx.x; b < ncb; b += 256) {
        int c = cnt[b];
        if (c) gbase[(size_t)blockIdx.x * ncb + b] = atomicAdd(&gcount[b], c);
    }
}

// ---------------- scatter edges into coarse-bin order (in-LDS goff scan) ----------------
__global__ __launch_bounds__(256) void k_scatter(const int* __restrict__ ei, const float* __restrict__ ew,
                                                 const int* __restrict__ gcount, const int* __restrict__ gbase,
                                                 u64* __restrict__ bkv, int E, int ncb)
{
    __shared__ int goffL[512];
    __shared__ int cnt[512];
    int t = threadIdx.x, lane = t & 63;
    if (t < 64) {
        int carry = 0;
        for (int base = 0; base < ncb; base += 64) {
            int i = base + lane;
            int v = (i < ncb) ? gcount[i] : 0;
            int inc = wscan_incl(v, lane);
            if (i < ncb) goffL[i] = carry + inc - v;
            carry += __shfl(inc, 63, 64);
        }
    }
    for (int i = t; i < ncb; i += 256) cnt[i] = 0;
    __syncthreads();
    int base = blockIdx.x * CHUNK;
    int lim = base + CHUNK < E ? base + CHUNK : E;
    for (int e = base + t; e < lim; e += 256) {
        int s = ei[e];
        int d = ei[(size_t)E + e];
        int b = d >> 8;
        int r = atomicAdd(&cnt[b], 1);
        int pos = goffL[b] + gbase[(size_t)blockIdx.x * ncb + b] + r;
        u32 key = ((u32)s << 8) | (u32)(d & 255);
        u32 wb; __builtin_memcpy(&wb, &ew[e], 4);
        bkv[pos] = ((u64)key << 32) | (u64)wb;
    }
}

// ---------------- fine pass: per coarse bin -> rowptr, dinv, cv (raw weights) ----------------
__global__ __launch_bounds__(256) void k_fine(const u64* __restrict__ bkv, const int* __restrict__ gcount,
                                              int* __restrict__ rowptr, float* __restrict__ dinv,
                                              int2* __restrict__ cv, int N, int ncb)
{
    __shared__ int goffL[513];
    __shared__ int cnt[256];
    __shared__ float wsum[256];
    __shared__ u16 lrank[CAP];
    __shared__ int lrp[256];
    __shared__ int wtot[4];
    int b = blockIdx.x, t = threadIdx.x;
    int lane = t & 63, wv = t >> 6;
    if (t < 64) {
        int carry = 0;
        for (int base = 0; base < ncb; base += 64) {
            int i = base + lane;
            int v = (i < ncb) ? gcount[i] : 0;
            int inc = wscan_incl(v, lane);
            if (i < ncb) goffL[i] = carry + inc - v;
            carry += __shfl(inc, 63, 64);
        }
        if (lane == 0) goffL[ncb] = carry;
    }
    cnt[t] = 0; wsum[t] = 0.f;
    __syncthreads();
    int s0 = goffL[b], s1 = goffL[b + 1];
    int n = s1 - s0;
    for (int i = t; i < n; i += 256) {
        u64 kv = bkv[s0 + i];
        int bin = (int)((kv >> 32) & 255);
        u32 wb = (u32)kv; float w; __builtin_memcpy(&w, &wb, 4);
        int r = atomicAdd(&cnt[bin], 1);
        if (i < CAP) lrank[i] = (u16)r;
        atomicAdd(&wsum[bin], w);
    }
    __syncthreads();
    int v = cnt[t];
    int inc = wscan_incl(v, lane);
    if (lane == 63) wtot[wv] = inc;
    __syncthreads();
    int woff = 0;
#pragma unroll
    for (int w = 0; w < 4; ++w) woff += (w < wv) ? wtot[w] : 0;
    int excl = woff + inc - v;
    lrp[t] = excl;
    int d = b * 256 + t;
    if (d < N) {
        rowptr[d] = s0 + excl;
        dinv[d] = rsqrtf(wsum[t] + 1.0f);     // +1 = self-loop weight
    }
    __syncthreads();
    for (int i = t; i < n; i += 256) {
        if (i >= CAP) break;
        u64 kv = bkv[s0 + i];
        int key = (int)(kv >> 32);
        int bin = key & 255;
        int src = key >> 8;
        int pos = s0 + lrp[bin] + (int)lrank[i];
        cv[pos] = make_int2(src, (int)(u32)kv);   // raw ew; norm folded into gather
    }
}

// ---------------- GEMM body: H[N,128](bf16) = f(X) @ W ----------------
template <int FUSE_BN, int INB>
__device__ __forceinline__ void gemm_body(const void* __restrict__ Xv, const u16* __restrict__ Wt,
                                          u16* __restrict__ H, int N, const float* __restrict__ ss, int bid)
{
    int tid = threadIdx.x;
    int wv = tid >> 6, lane = tid & 63;
    int colA = lane & 15, oct = lane >> 4;
    int r0 = bid * 64;
    int c0 = wv * 32;

    bf16x8 bfr[2][4];
#pragma unroll
    for (int t = 0; t < 2; ++t)
#pragma unroll
        for (int kk = 0; kk < 4; ++kk)
            bfr[t][kk] = *(const bf16x8*)(Wt + (size_t)(c0 + t * 16 + colA) * D + kk * 32 + oct * 8);

    float4 sc[8], sh[8];
    if (FUSE_BN) {
#pragma unroll
        for (int kk = 0; kk < 4; ++kk) {
            sc[kk * 2 + 0] = *(const float4*)(ss + kk * 32 + oct * 8);
            sc[kk * 2 + 1] = *(const float4*)(ss + kk * 32 + oct * 8 + 4);
            sh[kk * 2 + 0] = *(const float4*)(ss + D + kk * 32 + oct * 8);
            sh[kk * 2 + 1] = *(const float4*)(ss + D + kk * 32 + oct * 8 + 4);
        }
    }

    for (int rs = 0; rs < 4; ++rs) {
        int r = r0 + rs * 16;
        int rr = r + colA; rr = rr < N ? rr : N - 1;          // clamp loads; stores guarded
        f32x4 acc0 = {0.f, 0.f, 0.f, 0.f}, acc1 = {0.f, 0.f, 0.f, 0.f};
#pragma unroll
        for (int kk = 0; kk < 4; ++kk) {
            bf16x8 a;
            if (!INB) {
                const float* xrow = (const float*)Xv + (size_t)rr * D + oct * 8;
                float4 xa = *(const float4*)(xrow + kk * 32);
                float4 xb = *(const float4*)(xrow + kk * 32 + 4);
                a[0] = (short)f2bf(xa.x); a[1] = (short)f2bf(xa.y);
                a[2] = (short)f2bf(xa.z); a[3] = (short)f2bf(xa.w);
                a[4] = (short)f2bf(xb.x); a[5] = (short)f2bf(xb.y);
                a[6] = (short)f2bf(xb.z); a[7] = (short)f2bf(xb.w);
            } else {
                const u16* brow = (const u16*)Xv + (size_t)rr * D + oct * 8;
                bf16x8 v = *(const bf16x8*)(brow + kk * 32);
                if (FUSE_BN) {
                    float4 s0 = sc[kk * 2], s1 = sc[kk * 2 + 1];
                    float4 h0 = sh[kk * 2], h1 = sh[kk * 2 + 1];
                    a[0] = (short)f2bf(fmaxf(fmaf(bf2f((u16)v[0]), s0.x, h0.x), 0.f));
                    a[1] = (short)f2bf(fmaxf(fmaf(bf2f((u16)v[1]), s0.y, h0.y), 0.f));
                    a[2] = (short)f2bf(fmaxf(fmaf(bf2f((u16)v[2]), s0.z, h0.z), 0.f));
                    a[3] = (short)f2bf(fmaxf(fmaf(bf2f((u16)v[3]), s0.w, h0.w), 0.f));
                    a[4] = (short)f2bf(fmaxf(fmaf(bf2f((u16)v[4]), s1.x, h1.x), 0.f));
                    a[5] = (short)f2bf(fmaxf(fmaf(bf2f((u16)v[5]), s1.y, h1.y), 0.f));
                    a[6] = (short)f2bf(fmaxf(fmaf(bf2f((u16)v[6]), s1.z, h1.z), 0.f));
                    a[7] = (short)f2bf(fmaxf(fmaf(bf2f((u16)v[7]), s1.w, h1.w), 0.f));
                } else {
                    a = v;
                }
            }
            acc0 = __builtin_amdgcn_mfma_f32_16x16x32_bf16(a, bfr[0][kk], acc0, 0, 0, 0);
            acc1 = __builtin_amdgcn_mfma_f32_16x16x32_bf16(a, bfr[1][kk], acc1, 0, 0, 0);
        }
        int orow = r + oct * 4;
        size_t obase = (size_t)orow * D + c0 + colA;
#pragma unroll
        for (int j = 0; j < 4; ++j) {
            if (orow + j < N) {
                H[obase + (size_t)j * D]      = f2bf(acc0[j]);
                H[obase + (size_t)j * D + 16] = f2bf(acc1[j]);
            }
        }
    }
}

template <int FUSE_BN, int INB>
__global__ __launch_bounds__(256) void k_gemm(const void* __restrict__ Xv, const u16* __restrict__ Wt,
                                              u16* __restrict__ H, int N, const float* __restrict__ ss)
{
    gemm_body<FUSE_BN, INB>(Xv, Wt, H, N, ss, blockIdx.x);
}

// ---------------- bf16 gather + fused norm + BN partial stats (8-deep unroll) ----------------
// OUTB=1: write bf16 to outb; OUTB=0: write f32 to outf (layer 3)
template <int OUTB>
__global__ __launch_bounds__(256) void k_gather(const u16* __restrict__ h, const int* __restrict__ rowptr,
                                                const int2* __restrict__ cv, const float* __restrict__ dinv,
                                                const float* __restrict__ bias, u16* __restrict__ outb,
                                                float* __restrict__ outf, float* __restrict__ partial,
                                                int N, int nbg)
{
    int lane = threadIdx.x & 63, wv = threadIdx.x >> 6;
    float2 b = ((const float2*)bias)[lane];
    float4 st = {0.f, 0.f, 0.f, 0.f};
    for (int wid = blockIdx.x * 4 + wv; wid < N; wid += nbg * 4) {
        float dd = dinv[wid];
        float sw = dd * dd;
        ushort2 hv = ((const ushort2*)(h + (size_t)wid * D))[lane];
        float ax = bf2f(hv.x) * sw, ay = bf2f(hv.y) * sw;
        int j   = __builtin_amdgcn_readfirstlane(rowptr[wid]);
        int end = __builtin_amdgcn_readfirstlane(rowptr[wid + 1]);
        for (; j + 8 <= end; j += 8) {
            ushort2 v[8]; float w[8];
#pragma unroll
            for (int t = 0; t < 8; ++t) {
                int2 e = cv[j + t];
                w[t] = __int_as_float(e.y) * dinv[e.x] * dd;
                v[t] = ((const ushort2*)(h + (size_t)e.x * D))[lane];
            }
#pragma unroll
            for (int t = 0; t < 8; ++t) {
                ax = fmaf(w[t], bf2f(v[t].x), ax);
                ay = fmaf(w[t], bf2f(v[t].y), ay);
            }
        }
        for (; j + 4 <= end; j += 4) {
            ushort2 v[4]; float w[4];
#pragma unroll
            for (int t = 0; t < 4; ++t) {
                int2 e = cv[j + t];
                w[t] = __int_as_float(e.y) * dinv[e.x] * dd;
                v[t] = ((const ushort2*)(h + (size_t)e.x * D))[lane];
            }
#pragma unroll
            for (int t = 0; t < 4; ++t) {
                ax = fmaf(w[t], bf2f(v[t].x), ax);
                ay = fmaf(w[t], bf2f(v[t].y), ay);
            }
        }
        for (; j < end; ++j) {
            int2 e0 = cv[j];
            float w0 = __int_as_float(e0.y) * dinv[e0.x] * dd;
            ushort2 v0 = ((const ushort2*)(h + (size_t)e0.x * D))[lane];
            ax = fmaf(w0, bf2f(v0.x), ax); ay = fmaf(w0, bf2f(v0.y), ay);
        }
        float ox = ax + b.x, oy = ay + b.y;
        if (OUTB) {
            ushort2 ob; ob.x = f2bf(ox); ob.y = f2bf(oy);
            ((ushort2*)(outb + (size_t)wid * D))[lane] = ob;
        } else {
            float2 o; o.x = ox; o.y = oy;
            ((float2*)(outf + (size_t)wid * D))[lane] = o;
        }
        st.x += ox; st.y = fmaf(ox, ox, st.y);
        st.z += oy; st.w = fmaf(oy, oy, st.w);
    }
    __shared__ float4 red[4][64];
    red[wv][lane] = st;
    __syncthreads();
    if (wv == 0) {
        float4 a0 = red[0][lane], a1 = red[1][lane], a2 = red[2][lane], a3 = red[3][lane];
        float4 t;
        t.x = a0.x + a1.x + a2.x + a3.x;
        t.y = a0.y + a1.y + a2.y + a3.y;
        t.z = a0.z + a1.z + a2.z + a3.z;
        t.w = a0.w + a1.w + a2.w + a3.w;
        ((float4*)partial)[(size_t)blockIdx.x * 64 + lane] = t;
    }
}

// ---------------- reduce partials -> BN scale/shift ----------------
__global__ __launch_bounds__(256) void k_bnred(const float* __restrict__ partial, int nbg,
                                               const float* __restrict__ g, const float* __restrict__ be,
                                               float* __restrict__ ss, float invN)
{
    int c = blockIdx.x;
    int q = (c >> 1) * 4 + ((c & 1) << 1);
    int t = threadIdx.x;
    float s = 0.f, s2 = 0.f;
    for (int bb = t; bb < nbg; bb += 256) {
        const float* row = partial + (size_t)bb * 256 + q;
        s += row[0]; s2 += row[1];
    }
#pragma unroll
    for (int off = 32; off; off >>= 1) {
        s  += __shfl_down(s,  (unsigned)off, 64);
        s2 += __shfl_down(s2, (unsigned)off, 64);
    }
    __shared__ float rs_[4], rq_[4];
    int wv = t >> 6, lane = t & 63;
    if (lane == 0) { rs_[wv] = s; rq_[wv] = s2; }
    __syncthreads();
    if (t == 0) {
        float S = rs_[0] + rs_[1] + rs_[2] + rs_[3];
        float Q = rq_[0] + rq_[1] + rq_[2] + rq_[3];
        float mu = S * invN;
        float var = fmaxf(Q * invN - mu * mu, 0.f);
        float r = rsqrtf(var + BN_EPS);
        float sc = r * g[c];
        ss[c] = sc;
        ss[D + c] = be[c] - mu * sc;
    }
}

// final BN apply: f32 in-place
__global__ __launch_bounds__(256) void k_bnapply(const float* __restrict__ in, const float* __restrict__ ss,
                                                 float* __restrict__ out, int N)
{
    int idx = blockIdx.x * 256 + threadIdx.x;
    if (idx >= N * 32) return;
    int cc = idx & 31;
    float4 xv = ((const float4*)in)[idx];
    float4 sc = ((const float4*)ss)[cc];
    float4 sh = ((const float4*)(ss + D))[cc];
    float4 o;
    o.x = fmaf(xv.x, sc.x, sh.x);
    o.y = fmaf(xv.y, sc.y, sh.y);
    o.z = fmaf(xv.z, sc.z, sh.z);
    o.w = fmaf(xv.w, sc.w, sh.w);
    ((float4*)out)[idx] = o;
}

// ---------------- launch ----------------
extern "C" void kernel_launch(void* const* d_in, const int* in_sizes, int n_in,
                              void* d_out, int out_size, void* d_ws, size_t ws_size,
                              hipStream_t stream)
{
    const float* x  = (const float*)d_in[0];
    const int*   ei = (const int*)d_in[1];      // int32 on device
    const float* ew = (const float*)d_in[2];
    const float* W1 = (const float*)d_in[4];
    const float* b1 = (const float*)d_in[5];
    const float* W2 = (const float*)d_in[6];
    const float* b2 = (const float*)d_in[7];
    const float* W3 = (const float*)d_in[8];
    const float* b3 = (const float*)d_in[9];
    const float* g1 = (const float*)d_in[10];
    const float* be1 = (const float*)d_in[11];
    const float* g2 = (const float*)d_in[12];
    const float* be2 = (const float*)d_in[13];
    const float* g3 = (const float*)d_in[14];
    const float* be3 = (const float*)d_in[15];

    int N = in_sizes[0] / D;
    int E = in_sizes[1] / 2;
    float* P  = (float*)d_out;                       // final f32 output
    u16*   Pb = (u16*)d_out;                         // bf16 inter-layer activations [0, 25.6MB)
    u64*   bkv = (u64*)((char*)d_out + ((size_t)32 << 20));  // binned edges (CSR build only)

    char* ws = (char*)d_ws;
    size_t off = 0;
    auto alloc = [&](size_t bytes) -> void* {
        void* p = ws + off;
        off = (off + bytes + 255) & ~(size_t)255;
        return p;
    };
    int ncb = (N + 255) >> 8;                        // coarse bins (256 dsts each)
    int hb  = (E + CHUNK - 1) / CHUNK;               // h1/scatter blocks
    u16*   Hb    = (u16*)alloc((size_t)N * D * 2);   // bf16 GEMM output
    float* dinv  = (float*)alloc((size_t)N * 4);
    int*   rowptr= (int*)alloc((size_t)(N + 1) * 4);
    int2*  cv    = (int2*)alloc((size_t)E * 8);      // (src, raw ew)
    float* partial = (float*)alloc((size_t)NBG * 256 * 4);
    int*   gcount= (int*)alloc((size_t)(ncb + 1) * 4);
    int*   gbase = (int*)alloc((size_t)hb * ncb * 4);
    float* ss1   = (float*)alloc(1024);
    float* ss2   = (float*)alloc(1024);
    float* ss3   = (float*)alloc(1024);
    u16*   Wt1   = (u16*)alloc((size_t)D * D * 2);
    u16*   Wt2   = (u16*)alloc((size_t)D * D * 2);
    u16*   Wt3   = (u16*)alloc((size_t)D * D * 2);

    float invN = 1.0f / (float)N;
    int ggrid = (N + 63) / 64;
    int pgrid = (N * 32 + 255) / 256;
    int nbg   = NBG;
    int zgrid = (ncb + 256) / 256;

    // ---- prep: weights + zero gcount (+rowptr[N]=E), gemm0, counting-sort CSR build ----
    k_wtz<<<192 + zgrid, 256, 0, stream>>>(W1, W2, W3, Wt1, Wt2, Wt3, gcount, ncb, rowptr + N, E);
    k_gemm<0, 0><<<ggrid, 256, 0, stream>>>(x, Wt1, Hb, N, nullptr);
    k_h1<<<hb, 256, 0, stream>>>(ei, gcount, gbase, E, ncb);
    k_scatter<<<hb, 256, 0, stream>>>(ei, ew, gcount, gbase, bkv, E, ncb);
    k_fine<<<ncb, 256, 0, stream>>>(bkv, gcount, rowptr, dinv, cv, N, ncb);

    // ---- layer 1 ----
    k_gather<1><<<nbg, 256, 0, stream>>>(Hb, rowptr, cv, dinv, b1, Pb, nullptr, partial, N, nbg);
    k_bnred<<<D, 256, 0, stream>>>(partial, nbg, g1, be1, ss1, invN);

    // ---- layer 2 (BN1+ReLU fused into gemm, bf16 in) ----
    k_gemm<1, 1><<<ggrid, 256, 0, stream>>>(Pb, Wt2, Hb, N, ss1);
    k_gather<1><<<nbg, 256, 0, stream>>>(Hb, rowptr, cv, dinv, b2, Pb, nullptr, partial, N, nbg);
    k_bnred<<<D, 256, 0, stream>>>(partial, nbg, g2, be2, ss2, invN);

    // ---- layer 3 (BN2+ReLU fused; bf16 gather -> f32 P; final BN in-place) ----
    k_gemm<1, 1><<<ggrid, 256, 0, stream>>>(Pb, Wt3, Hb, N, ss2);
    k_gather<0><<<nbg, 256, 0, stream>>>(Hb, rowptr, cv, dinv, b3, nullptr, P, partial, N, nbg);
    k_bnred<<<D, 256, 0, stream>>>(partial, nbg, g3, be3, ss3, invN);
    k_bnapply<<<pgrid, 256, 0, stream>>>(P, ss3, P, N);
}

// Round 17
// 405.799 us; speedup vs baseline: 1.7157x; 1.0164x over previous
//
#include <hip/hip_runtime.h>
#include <hip/hip_bf16.h>

#define D 128
#define BN_EPS 1e-5f
#define NBG 2048                   // gather grid blocks
#define CHUNK 4096                 // edges per block in h1/scatter
#define CAP 6144                   // max edges per coarse bin

typedef unsigned short u16;
typedef unsigned int u32;
typedef unsigned long long u64;
typedef __attribute__((ext_vector_type(8))) short bf16x8;
typedef __attribute__((ext_vector_type(4))) float f32x4;

__device__ __forceinline__ float bf2f(u16 u) {
    unsigned v = (unsigned)u << 16; float f; __builtin_memcpy(&f, &v, 4); return f;
}
__device__ __forceinline__ u16 f2bf(float f) {
    __hip_bfloat16 h = __float2bfloat16(f);
    u16 r; __builtin_memcpy(&r, &h, 2); return r;
}

__device__ __forceinline__ int wscan_incl(int v, int lane) {
    int inc = v;
#pragma unroll
    for (int off = 1; off < 64; off <<= 1) {
        int t = __shfl_up(inc, (unsigned)off, 64);
        if (lane >= off) inc += t;
    }
    return inc;
}

// ---------------- fused: W^T->bf16 (x3) + zero gcount + rowptr[N]=E ----------------
__global__ __launch_bounds__(256) void k_wtz(const float* __restrict__ W1, const float* __restrict__ W2,
                                             const float* __restrict__ W3, u16* __restrict__ Wt1,
                                             u16* __restrict__ Wt2, u16* __restrict__ Wt3,
                                             int* __restrict__ zp, int nz, int* __restrict__ rowptrN, int E)
{
    int bid = blockIdx.x;
    if (bid < 192) {
        int w = bid >> 6;
        int i = (bid & 63) * 256 + threadIdx.x;     // i = k*128 + c
        int k = i >> 7, c = i & 127;
        const float* W = w == 0 ? W1 : (w == 1 ? W2 : W3);
        u16* Wt = w == 0 ? Wt1 : (w == 1 ? Wt2 : Wt3);
        Wt[c * D + k] = f2bf(W[i]);
    } else {
        if (bid == 192 && threadIdx.x == 0) *rowptrN = E;
        int i = (bid - 192) * 256 + threadIdx.x;
        if (i < nz) zp[i] = 0;
    }
}

// ---------------- counting sort level 1: coarse histogram (LDS) ----------------
__global__ __launch_bounds__(256) void k_h1(const int* __restrict__ ei, int* __restrict__ gcount,
                                            int* __restrict__ gbase, int E, int ncb)
{
    __shared__ int cnt[512];
    for (int i = threadIdx.x; i < ncb; i += 256) cnt[i] = 0;
    __syncthreads();
    int base = blockIdx.x * CHUNK;
    int lim = base + CHUNK < E ? base + CHUNK : E;
    for (int e = base + threadIdx.x; e < lim; e += 256) {
        int d = ei[(size_t)E + e];
        atomicAdd(&cnt[d >> 8], 1);
    }
    __syncthreads();
    for (int b = threadIdx.x; b < ncb; b += 256) {
        int c = cnt[b];
        if (c) gbase[(size_t)blockIdx.x * ncb + b] = atomicAdd(&gcount[b], c);
    }
}

// ---------------- scatter edges into coarse-bin order (in-LDS goff scan) ----------------
__global__ __launch_bounds__(256) void k_scatter(const int* __restrict__ ei, const float* __restrict__ ew,
                                                 const int* __restrict__ gcount, const int* __restrict__ gbase,
                                                 u64* __restrict__ bkv, int E, int ncb)
{
    __shared__ int goffL[512];
    __shared__ int cnt[512];
    int t = threadIdx.x, lane = t & 63;
    if (t < 64) {
        int carry = 0;
        for (int base = 0; base < ncb; base += 64) {
            int i = base + lane;
            int v = (i < ncb) ? gcount[i] : 0;
            int inc = wscan_incl(v, lane);
            if (i < ncb) goffL[i] = carry + inc - v;
            carry += __shfl(inc, 63, 64);
        }
    }
    for (int i = t; i < ncb; i += 256) cnt[i] = 0;
    __syncthreads();
    int base = blockIdx.x * CHUNK;
    int lim = base + CHUNK < E ? base + CHUNK : E;
    for (int e = base + t; e < lim; e += 256) {
        int s = ei[e];
        int d = ei[(size_t)E + e];
        int b = d >> 8;
        int r = atomicAdd(&cnt[b], 1);
        int pos = goffL[b] + gbase[(size_t)blockIdx.x * ncb + b] + r;
        u32 key = ((u32)s << 8) | (u32)(d & 255);
        u32 wb; __builtin_memcpy(&wb, &ew[e], 4);
        bkv[pos] = ((u64)key << 32) | (u64)wb;
    }
}

// ---------------- fine pass: per coarse bin -> rowptr, dinv, cv (raw weights) ----------------
__global__ __launch_bounds__(256) void k_fine(const u64* __restrict__ bkv, const int* __restrict__ gcount,
                                              int* __restrict__ rowptr, float* __restrict__ dinv,
                                              int2* __restrict__ cv, int N, int ncb)
{
    __shared__ int goffL[513];
    __shared__ int cnt[256];
    __shared__ float wsum[256];
    __shared__ u16 lrank[CAP];
    __shared__ int lrp[256];
    __shared__ int wtot[4];
    int b = blockIdx.x, t = threadIdx.x;
    int lane = t & 63, wv = t >> 6;
    if (t < 64) {
        int carry = 0;
        for (int base = 0; base < ncb; base += 64) {
            int i = base + lane;
            int v = (i < ncb) ? gcount[i] : 0;
            int inc = wscan_incl(v, lane);
            if (i < ncb) goffL[i] = carry + inc - v;
            carry += __shfl(inc, 63, 64);
        }
        if (lane == 0) goffL[ncb] = carry;
    }
    cnt[t] = 0; wsum[t] = 0.f;
    __syncthreads();
    int s0 = goffL[b], s1 = goffL[b + 1];
    int n = s1 - s0;
    for (int i = t; i < n; i += 256) {
        u64 kv = bkv[s0 + i];
        int bin = (int)((kv >> 32) & 255);
        u32 wb = (u32)kv; float w; __builtin_memcpy(&w, &wb, 4);
        int r = atomicAdd(&cnt[bin], 1);
        if (i < CAP) lrank[i] = (u16)r;
        atomicAdd(&wsum[bin], w);
    }
    __syncthreads();
    int v = cnt[t];
    int inc = wscan_incl(v, lane);
    if (lane == 63) wtot[wv] = inc;
    __syncthreads();
    int woff = 0;
#pragma unroll
    for (int w = 0; w < 4; ++w) woff += (w < wv) ? wtot[w] : 0;
    int excl = woff + inc - v;
    lrp[t] = excl;
    int d = b * 256 + t;
    if (d < N) {
        rowptr[d] = s0 + excl;
        dinv[d] = rsqrtf(wsum[t] + 1.0f);     // +1 = self-loop weight
    }
    __syncthreads();
    for (int i = t; i < n; i += 256) {
        if (i >= CAP) break;
        u64 kv = bkv[s0 + i];
        int key = (int)(kv >> 32);
        int bin = key & 255;
        int src = key >> 8;
        int pos = s0 + lrp[bin] + (int)lrank[i];
        cv[pos] = make_int2(src, (int)(u32)kv);   // raw ew; normalized by k_norm
    }
}

// ---------------- norm pass: val *= dinv[src]*dinv[dst] (once, amortized over 3 gathers) ------
__global__ __launch_bounds__(256) void k_norm(const int* __restrict__ rowptr, const float* __restrict__ dinv,
                                              int2* __restrict__ cv, int N)
{
    int wid = blockIdx.x * 4 + (threadIdx.x >> 6);
    int lane = threadIdx.x & 63;
    if (wid >= N) return;
    float dd = dinv[wid];
    int s = __builtin_amdgcn_readfirstlane(rowptr[wid]);
    int e = __builtin_amdgcn_readfirstlane(rowptr[wid + 1]);
    for (int j = s + lane; j < e; j += 64) {
        int2 ev = cv[j];
        float w = __int_as_float(ev.y);
        cv[j] = make_int2(ev.x, __float_as_int(w * dinv[ev.x] * dd));
    }
}

// ---------------- GEMM body: H[N,128](bf16) = f(X) @ W ----------------
template <int FUSE_BN, int INB>
__device__ __forceinline__ void gemm_body(const void* __restrict__ Xv, const u16* __restrict__ Wt,
                                          u16* __restrict__ H, int N, const float* __restrict__ ss, int bid)
{
    int tid = threadIdx.x;
    int wv = tid >> 6, lane = tid & 63;
    int colA = lane & 15, oct = lane >> 4;
    int r0 = bid * 64;
    int c0 = wv * 32;

    bf16x8 bfr[2][4];
#pragma unroll
    for (int t = 0; t < 2; ++t)
#pragma unroll
        for (int kk = 0; kk < 4; ++kk)
            bfr[t][kk] = *(const bf16x8*)(Wt + (size_t)(c0 + t * 16 + colA) * D + kk * 32 + oct * 8);

    float4 sc[8], sh[8];
    if (FUSE_BN) {
#pragma unroll
        for (int kk = 0; kk < 4; ++kk) {
            sc[kk * 2 + 0] = *(const float4*)(ss + kk * 32 + oct * 8);
            sc[kk * 2 + 1] = *(const float4*)(ss + kk * 32 + oct * 8 + 4);
            sh[kk * 2 + 0] = *(const float4*)(ss + D + kk * 32 + oct * 8);
            sh[kk * 2 + 1] = *(const float4*)(ss + D + kk * 32 + oct * 8 + 4);
        }
    }

    for (int rs = 0; rs < 4; ++rs) {
        int r = r0 + rs * 16;
        int rr = r + colA; rr = rr < N ? rr : N - 1;          // clamp loads; stores guarded
        f32x4 acc0 = {0.f, 0.f, 0.f, 0.f}, acc1 = {0.f, 0.f, 0.f, 0.f};
#pragma unroll
        for (int kk = 0; kk < 4; ++kk) {
            bf16x8 a;
            if (!INB) {
                const float* xrow = (const float*)Xv + (size_t)rr * D + oct * 8;
                float4 xa = *(const float4*)(xrow + kk * 32);
                float4 xb = *(const float4*)(xrow + kk * 32 + 4);
                a[0] = (short)f2bf(xa.x); a[1] = (short)f2bf(xa.y);
                a[2] = (short)f2bf(xa.z); a[3] = (short)f2bf(xa.w);
                a[4] = (short)f2bf(xb.x); a[5] = (short)f2bf(xb.y);
                a[6] = (short)f2bf(xb.z); a[7] = (short)f2bf(xb.w);
            } else {
                const u16* brow = (const u16*)Xv + (size_t)rr * D + oct * 8;
                bf16x8 v = *(const bf16x8*)(brow + kk * 32);
                if (FUSE_BN) {
                    float4 s0 = sc[kk * 2], s1 = sc[kk * 2 + 1];
                    float4 h0 = sh[kk * 2], h1 = sh[kk * 2 + 1];
                    a[0] = (short)f2bf(fmaxf(fmaf(bf2f((u16)v[0]), s0.x, h0.x), 0.f));
                    a[1] = (short)f2bf(fmaxf(fmaf(bf2f((u16)v[1]), s0.y, h0.y), 0.f));
                    a[2] = (short)f2bf(fmaxf(fmaf(bf2f((u16)v[2]), s0.z, h0.z), 0.f));
                    a[3] = (short)f2bf(fmaxf(fmaf(bf2f((u16)v[3]), s0.w, h0.w), 0.f));
                    a[4] = (short)f2bf(fmaxf(fmaf(bf2f((u16)v[4]), s1.x, h1.x), 0.f));
                    a[5] = (short)f2bf(fmaxf(fmaf(bf2f((u16)v[5]), s1.y, h1.y), 0.f));
                    a[6] = (short)f2bf(fmaxf(fmaf(bf2f((u16)v[6]), s1.z, h1.z), 0.f));
                    a[7] = (short)f2bf(fmaxf(fmaf(bf2f((u16)v[7]), s1.w, h1.w), 0.f));
                } else {
                    a = v;
                }
            }
            acc0 = __builtin_amdgcn_mfma_f32_16x16x32_bf16(a, bfr[0][kk], acc0, 0, 0, 0);
            acc1 = __builtin_amdgcn_mfma_f32_16x16x32_bf16(a, bfr[1][kk], acc1, 0, 0, 0);
        }
        int orow = r + oct * 4;
        size_t obase = (size_t)orow * D + c0 + colA;
#pragma unroll
        for (int j = 0; j < 4; ++j) {
            if (orow + j < N) {
                H[obase + (size_t)j * D]      = f2bf(acc0[j]);
                H[obase + (size_t)j * D + 16] = f2bf(acc1[j]);
            }
        }
    }
}

template <int FUSE_BN, int INB>
__global__ __launch_bounds__(256) void k_gemm(const void* __restrict__ Xv, const u16* __restrict__ Wt,
                                              u16* __restrict__ H, int N, const float* __restrict__ ss)
{
    gemm_body<FUSE_BN, INB>(Xv, Wt, H, N, ss, blockIdx.x);
}

// ---------------- bf16 gather (normalized cv) + BN partial stats (8-deep unroll) ----------------
// OUTB=1: write bf16 to outb; OUTB=0: write f32 to outf (layer 3)
template <int OUTB>
__global__ __launch_bounds__(256) void k_gather(const u16* __restrict__ h, const int* __restrict__ rowptr,
                                                const int2* __restrict__ cv, const float* __restrict__ dinv,
                                                const float* __restrict__ bias, u16* __restrict__ outb,
                                                float* __restrict__ outf, float* __restrict__ partial,
                                                int N, int nbg)
{
    int lane = threadIdx.x & 63, wv = threadIdx.x >> 6;
    float2 b = ((const float2*)bias)[lane];
    float4 st = {0.f, 0.f, 0.f, 0.f};
    for (int wid = blockIdx.x * 4 + wv; wid < N; wid += nbg * 4) {
        float di = dinv[wid];
        float sw = di * di;                     // self-loop norm (ew = 1)
        ushort2 hv = ((const ushort2*)(h + (size_t)wid * D))[lane];
        float ax = bf2f(hv.x) * sw, ay = bf2f(hv.y) * sw;
        int j   = __builtin_amdgcn_readfirstlane(rowptr[wid]);
        int end = __builtin_amdgcn_readfirstlane(rowptr[wid + 1]);
        for (; j + 8 <= end; j += 8) {
            ushort2 v[8]; float w[8];
#pragma unroll
            for (int t = 0; t < 8; ++t) {
                int2 e = cv[j + t];
                w[t] = __int_as_float(e.y);
                v[t] = ((const ushort2*)(h + (size_t)e.x * D))[lane];
            }
#pragma unroll
            for (int t = 0; t < 8; ++t) {
                ax = fmaf(w[t], bf2f(v[t].x), ax);
                ay = fmaf(w[t], bf2f(v[t].y), ay);
            }
        }
        for (; j + 4 <= end; j += 4) {
            ushort2 v[4]; float w[4];
#pragma unroll
            for (int t = 0; t < 4; ++t) {
                int2 e = cv[j + t];
                w[t] = __int_as_float(e.y);
                v[t] = ((const ushort2*)(h + (size_t)e.x * D))[lane];
            }
#pragma unroll
            for (int t = 0; t < 4; ++t) {
                ax = fmaf(w[t], bf2f(v[t].x), ax);
                ay = fmaf(w[t], bf2f(v[t].y), ay);
            }
        }
        for (; j < end; ++j) {
            int2 e0 = cv[j];
            float w0 = __int_as_float(e0.y);
            ushort2 v0 = ((const ushort2*)(h + (size_t)e0.x * D))[lane];
            ax = fmaf(w0, bf2f(v0.x), ax); ay = fmaf(w0, bf2f(v0.y), ay);
        }
        float ox = ax + b.x, oy = ay + b.y;
        if (OUTB) {
            ushort2 ob; ob.x = f2bf(ox); ob.y = f2bf(oy);
            ((ushort2*)(outb + (size_t)wid * D))[lane] = ob;
        } else {
            float2 o; o.x = ox; o.y = oy;
            ((float2*)(outf + (size_t)wid * D))[lane] = o;
        }
        st.x += ox; st.y = fmaf(ox, ox, st.y);
        st.z += oy; st.w = fmaf(oy, oy, st.w);
    }
    __shared__ float4 red[4][64];
    red[wv][lane] = st;
    __syncthreads();
    if (wv == 0) {
        float4 a0 = red[0][lane], a1 = red[1][lane], a2 = red[2][lane], a3 = red[3][lane];
        float4 t;
        t.x = a0.x + a1.x + a2.x + a3.x;
        t.y = a0.y + a1.y + a2.y + a3.y;
        t.z = a0.z + a1.z + a2.z + a3.z;
        t.w = a0.w + a1.w + a2.w + a3.w;
        ((float4*)partial)[(size_t)blockIdx.x * 64 + lane] = t;
    }
}

// ---------------- reduce partials -> BN scale/shift ----------------
__global__ __launch_bounds__(256) void k_bnred(const float* __restrict__ partial, int nbg,
                                               const float* __restrict__ g, const float* __restrict__ be,
                                               float* __restrict__ ss, float invN)
{
    int c = blockIdx.x;
    int q = (c >> 1) * 4 + ((c & 1) << 1);
    int t = threadIdx.x;
    float s = 0.f, s2 = 0.f;
    for (int bb = t; bb < nbg; bb += 256) {
        const float* row = partial + (size_t)bb * 256 + q;
        s += row[0]; s2 += row[1];
    }
#pragma unroll
    for (int off = 32; off; off >>= 1) {
        s  += __shfl_down(s,  (unsigned)off, 64);
        s2 += __shfl_down(s2, (unsigned)off, 64);
    }
    __shared__ float rs_[4], rq_[4];
    int wv = t >> 6, lane = t & 63;
    if (lane == 0) { rs_[wv] = s; rq_[wv] = s2; }
    __syncthreads();
    if (t == 0) {
        float S = rs_[0] + rs_[1] + rs_[2] + rs_[3];
        float Q = rq_[0] + rq_[1] + rq_[2] + rq_[3];
        float mu = S * invN;
        float var = fmaxf(Q * invN - mu * mu, 0.f);
        float r = rsqrtf(var + BN_EPS);
        float sc = r * g[c];
        ss[c] = sc;
        ss[D + c] = be[c] - mu * sc;
    }
}

// final BN apply: f32 in-place
__global__ __launch_bounds__(256) void k_bnapply(const float* __restrict__ in, const float* __restrict__ ss,
                                                 float* __restrict__ out, int N)
{
    int idx = blockIdx.x * 256 + threadIdx.x;
    if (idx >= N * 32) return;
    int cc = idx & 31;
    float4 xv = ((const float4*)in)[idx];
    float4 sc = ((const float4*)ss)[cc];
    float4 sh = ((const float4*)(ss + D))[cc];
    float4 o;
    o.x = fmaf(xv.x, sc.x, sh.x);
    o.y = fmaf(xv.y, sc.y, sh.y);
    o.z = fmaf(xv.z, sc.z, sh.z);
    o.w = fmaf(xv.w, sc.w, sh.w);
    ((float4*)out)[idx] = o;
}

// ---------------- launch ----------------
extern "C" void kernel_launch(void* const* d_in, const int* in_sizes, int n_in,
                              void* d_out, int out_size, void* d_ws, size_t ws_size,
                              hipStream_t stream)
{
    const float* x  = (const float*)d_in[0];
    const int*   ei = (const int*)d_in[1];      // int32 on device
    const float* ew = (const float*)d_in[2];
    const float* W1 = (const float*)d_in[4];
    const float* b1 = (const float*)d_in[5];
    const float* W2 = (const float*)d_in[6];
    const float* b2 = (const float*)d_in[7];
    const float* W3 = (const float*)d_in[8];
    const float* b3 = (const float*)d_in[9];
    const float* g1 = (const float*)d_in[10];
    const float* be1 = (const float*)d_in[11];
    const float* g2 = (const float*)d_in[12];
    const float* be2 = (const float*)d_in[13];
    const float* g3 = (const float*)d_in[14];
    const float* be3 = (const float*)d_in[15];

    int N = in_sizes[0] / D;
    int E = in_sizes[1] / 2;
    float* P  = (float*)d_out;                       // final f32 output
    u16*   Pb = (u16*)d_out;                         // bf16 inter-layer activations [0, 25.6MB)
    u64*   bkv = (u64*)((char*)d_out + ((size_t)32 << 20));  // binned edges (CSR build only)

    char* ws = (char*)d_ws;
    size_t off = 0;
    auto alloc = [&](size_t bytes) -> void* {
        void* p = ws + off;
        off = (off + bytes + 255) & ~(size_t)255;
        return p;
    };
    int ncb = (N + 255) >> 8;                        // coarse bins (256 dsts each)
    int hb  = (E + CHUNK - 1) / CHUNK;               // h1/scatter blocks
    u16*   Hb    = (u16*)alloc((size_t)N * D * 2);   // bf16 GEMM output
    float* dinv  = (float*)alloc((size_t)N * 4);
    int*   rowptr= (int*)alloc((size_t)(N + 1) * 4);
    int2*  cv    = (int2*)alloc((size_t)E * 8);      // (src, norm weight after k_norm)
    float* partial = (float*)alloc((size_t)NBG * 256 * 4);
    int*   gcount= (int*)alloc((size_t)(ncb + 1) * 4);
    int*   gbase = (int*)alloc((size_t)hb * ncb * 4);
    float* ss1   = (float*)alloc(1024);
    float* ss2   = (float*)alloc(1024);
    float* ss3   = (float*)alloc(1024);
    u16*   Wt1   = (u16*)alloc((size_t)D * D * 2);
    u16*   Wt2   = (u16*)alloc((size_t)D * D * 2);
    u16*   Wt3   = (u16*)alloc((size_t)D * D * 2);

    float invN = 1.0f / (float)N;
    int ggrid = (N + 63) / 64;
    int pgrid = (N * 32 + 255) / 256;
    int nbg   = NBG;
    int ngrid4 = (N + 3) / 4;
    int zgrid = (ncb + 256) / 256;

    // ---- prep: weights + zero gcount (+rowptr[N]=E), gemm0, counting-sort CSR build ----
    k_wtz<<<192 + zgrid, 256, 0, stream>>>(W1, W2, W3, Wt1, Wt2, Wt3, gcount, ncb, rowptr + N, E);
    k_gemm<0, 0><<<ggrid, 256, 0, stream>>>(x, Wt1, Hb, N, nullptr);
    k_h1<<<hb, 256, 0, stream>>>(ei, gcount, gbase, E, ncb);
    k_scatter<<<hb, 256, 0, stream>>>(ei, ew, gcount, gbase, bkv, E, ncb);
    k_fine<<<ncb, 256, 0, stream>>>(bkv, gcount, rowptr, dinv, cv, N, ncb);
    k_norm<<<ngrid4, 256, 0, stream>>>(rowptr, dinv, cv, N);

    // ---- layer 1 ----
    k_gather<1><<<nbg, 256, 0, stream>>>(Hb, rowptr, cv, dinv, b1, Pb, nullptr, partial, N, nbg);
    k_bnred<<<D, 256, 0, stream>>>(partial, nbg, g1, be1, ss1, invN);

    // ---- layer 2 (BN1+ReLU fused into gemm, bf16 in) ----
    k_gemm<1, 1><<<ggrid, 256, 0, stream>>>(Pb, Wt2, Hb, N, ss1);
    k_gather<1><<<nbg, 256, 0, stream>>>(Hb, rowptr, cv, dinv, b2, Pb, nullptr, partial, N, nbg);
    k_bnred<<<D, 256, 0, stream>>>(partial, nbg, g2, be2, ss2, invN);

    // ---- layer 3 (BN2+ReLU fused; bf16 gather -> f32 P; final BN in-place) ----
    k_gemm<1, 1><<<ggrid, 256, 0, stream>>>(Pb, Wt3, Hb, N, ss2);
    k_gather<0><<<nbg, 256, 0, stream>>>(Hb, rowptr, cv, dinv, b3, nullptr, P, partial, N, nbg);
    k_bnred<<<D, 256, 0, stream>>>(partial, nbg, g3, be3, ss3, invN);
    k_bnapply<<<pgrid, 256, 0, stream>>>(P, ss3, P, N);
}